// Round 7
// baseline (431.889 us; speedup 1.0000x reference)
//
#include <hip/hip_runtime.h>
#include <hip/hip_bf16.h>
#include <stdint.h>

// Problem constants
#define B_SZ   4096
#define IN_SZ  256
#define U_SZ   128
#define G_SZ   1000
#define LW_SZ  64
#define LB_SZ  32
#define K_SZ   (LW_SZ * IN_SZ)      // 16384

// out[B,U] = A[B,K] * Wf[K,U];  A[b, l*256+i] = zw[b,l] * x[b,i]
// LDS-free fragment-streaming GEMM, 32x32 wave tiles for 4 waves/SIMD,
// fused split-K reduction (atomic-counter serialized epilogue).
#define KSPL   16                   // l-split: 4 l's per block
#define NSTEP  16                   // s = c*4 + li
#define NTILE  (K_SZ / 64)          // 256 wfT k-tiles
#define TSH    8192                 // shorts per 64k x 128u tile / 128r x 64k chunk
#define NQ     128                  // reduction quadrants: 64 mt x 2 nt

typedef __attribute__((ext_vector_type(8))) short  bf16x8;
typedef __attribute__((ext_vector_type(4))) float  f32x4;
typedef __attribute__((ext_vector_type(8))) _Float16 f16x8;
typedef __attribute__((ext_vector_type(2))) _Float16 f16x2;

__device__ __forceinline__ ushort f2bf(float f) {
    unsigned u = __float_as_uint(f);
    u += 0x7fffu + ((u >> 16) & 1u);
    return (ushort)(u >> 16);
}

__device__ __forceinline__ float softplus_f(float v) {
    return fmaxf(v, 0.0f) + log1pf(__expf(-fabsf(v)));
}

__device__ __forceinline__ f16x8 mulzw(f16x8 a, f16x2 z) {
    union { f16x8 v8; f16x2 v2[4]; } in, out;
    in.v8 = a;
    #pragma unroll
    for (int w = 0; w < 4; ++w) out.v2[w] = in.v2[w] * z;   // v_pk_mul_f16
    return out.v8;
}

// ---------------------------------------------------------------------------
// Prep: fragment-order operand layouts + counter zeroing. 769 blocks.
//  [0,512):  Wf -> wfT f16; tile t, half h=kb: slot p = (kb*8+u16)*64 + l,
//            value = Wf[(t*64 + kb*32 + (l>>4)*8 + j)*128 + u16*16 + (l&15)]
//  [512,768): x -> xh f16; chunk bb=(mt128,c), half h: slot p = (r16*2+kb)*64+l,
//            value = x[(mt128*128 + r16*16 + (l&15))*256 + c*64 + kb*32 + (l>>4)*8 + j]
//  768: zero the NQ split-K counters.
// ---------------------------------------------------------------------------
__global__ __launch_bounds__(256) void fmd_prep7(
    const float* __restrict__ Wf, const float* __restrict__ x,
    short* __restrict__ wfT, short* __restrict__ xh, int* __restrict__ cnt)
{
    const int tid = threadIdx.x;
    const int bidx = blockIdx.x;
    if (bidx < 512) {
        const int t = bidx >> 1, h = bidx & 1;      // tile, kb-half
        __shared__ float lds[32 * 133];             // [kk][u] padded
        #pragma unroll
        for (int it = 0; it < 4; ++it) {
            int idx = it * 256 + tid;               // 1024 float4 slots
            int kk = idx >> 5, u4 = idx & 31;
            float4 v = *reinterpret_cast<const float4*>(
                &Wf[(t * 64 + h * 32 + kk) * U_SZ + u4 * 4]);
            *reinterpret_cast<float4*>(&lds[kk * 133 + u4 * 4]) = v;
        }
        __syncthreads();
        short* tile = wfT + t * TSH;
        #pragma unroll
        for (int it = 0; it < 2; ++it) {
            int p = h * 512 + it * 256 + tid;       // f16x8 slot
            int u16 = (p >> 6) & 7, l = p & 63;
            int u = u16 * 16 + (l & 15);
            int kk0 = (l >> 4) * 8;                 // local row (kb base in h)
            union { _Float16 hh[8]; f16x8 v; } pk;
            #pragma unroll
            for (int j = 0; j < 8; ++j)
                pk.hh[j] = (_Float16)lds[(kk0 + j) * 133 + u];
            *reinterpret_cast<f16x8*>(&tile[p * 8]) = pk.v;
        }
    } else if (bidx < 768) {
        const int e = bidx - 512;
        const int bb = e >> 1, h = e & 1;           // chunk, half
        const int mt128 = bb >> 2, c = bb & 3;
        short* tile = xh + bb * TSH;
        #pragma unroll
        for (int it = 0; it < 2; ++it) {
            int p = h * 512 + it * 256 + tid;       // f16x8 slot
            int frag = p >> 6, l = p & 63;
            int r16 = frag >> 1, kb = frag & 1;
            int row = mt128 * 128 + r16 * 16 + (l & 15);
            int col = c * 64 + kb * 32 + (l >> 4) * 8;
            const float* src = &x[row * IN_SZ + col];
            float4 a = *reinterpret_cast<const float4*>(src);
            float4 b = *reinterpret_cast<const float4*>(src + 4);
            union { _Float16 hh[8]; f16x8 v; } pk;
            pk.hh[0] = (_Float16)a.x; pk.hh[1] = (_Float16)a.y;
            pk.hh[2] = (_Float16)a.z; pk.hh[3] = (_Float16)a.w;
            pk.hh[4] = (_Float16)b.x; pk.hh[5] = (_Float16)b.y;
            pk.hh[6] = (_Float16)b.z; pk.hh[7] = (_Float16)b.w;
            *reinterpret_cast<f16x8*>(&tile[p * 8]) = pk.v;
        }
    } else {
        if (tid < NQ) cnt[tid] = 0;
    }
}

// ---------------------------------------------------------------------------
// GEMM v7: 2048 blocks = 64 mt x 2 nt x 16 ks; 4 waves (2x2) of 32x32 tiles.
// ~115 VGPR -> 4 waves/SIMD (2x the latency-hiding of v3..v6).
// LDS-free fragment streaming, double-buffered regs, zw via pk_mul.
// Fused split-K epilogue: f16 partial -> fence -> counter; last block of the
// (mt,nt) quadrant reduces 16 slices + bias and writes out (deterministic:
// fixed ks-order summation of identical f16 values).
// ---------------------------------------------------------------------------
__global__ __launch_bounds__(256, 4) void fmd_gemm7(
    const short* __restrict__ xh,
    const short* __restrict__ wfT,
    const float* __restrict__ zw_mu,
    const float* __restrict__ zw_sigma,
    const float* __restrict__ eps_w,
    const int*   __restrict__ gid,
    const float* __restrict__ Bf,
    const float* __restrict__ eps_b,
    const float* __restrict__ zb_mu,
    const float* __restrict__ zb_sigma,
    _Float16*    __restrict__ part,
    int*         __restrict__ cnt,
    float*       __restrict__ out)
{
    const int tid  = threadIdx.x;
    const int lane = tid & 63;
    const int wid  = tid >> 6;
    const int wrow = wid >> 1;          // 0..1
    const int wcol = wid & 1;           // 0..1
    const int bid  = blockIdx.x;
    const int ks   = bid & (KSPL - 1);
    const int q    = bid >> 4;          // quadrant 0..127
    const int mt   = q >> 1;            // 0..63 (64-row tiles)
    const int nt   = q & 1;             // 0..1  (64-col tiles)
    const int R0   = mt * 64;
    const int C0   = nt * 64;
    const int mt128 = mt >> 1;
    const int h128  = mt & 1;
    const int lane8 = lane * 8;

    __shared__ float zbs[64][33];       // reducer: sampled zb per row
    __shared__ float bfl[32][64];       // reducer: Bf slice [l][u-C0]
    __shared__ int   oldc_s;

    // --- per-lane packed zw: 2 m-rows x 4 li ---
    f16x2 zwp[2][4];
    #pragma unroll
    for (int m = 0; m < 2; ++m) {
        int row = wrow * 32 + m * 16 + (lane & 15);
        int b   = R0 + row;
        int g   = gid[b];
        float4 mu = *reinterpret_cast<const float4*>(&zw_mu[g * LW_SZ + ks * 4]);
        float4 sg = *reinterpret_cast<const float4*>(&zw_sigma[g * LW_SZ + ks * 4]);
        float4 ep = *reinterpret_cast<const float4*>(&eps_w[b * LW_SZ + ks * 4]);
        _Float16 h0 = (_Float16)(mu.x + softplus_f(sg.x) * ep.x);
        _Float16 h1 = (_Float16)(mu.y + softplus_f(sg.y) * ep.y);
        _Float16 h2 = (_Float16)(mu.z + softplus_f(sg.z) * ep.z);
        _Float16 h3 = (_Float16)(mu.w + softplus_f(sg.w) * ep.w);
        zwp[m][0] = (f16x2){h0, h0};
        zwp[m][1] = (f16x2){h1, h1};
        zwp[m][2] = (f16x2){h2, h2};
        zwp[m][3] = (f16x2){h3, h3};
    }

    f16x8 areg[2][2][2];   // [c&1][kb][m]
    f16x8 breg[2][2][2];   // [s&1][kb][n]

    // prologue: A(c=0), B(s=0)
    {
        const short* ap = xh + (mt128 * 4 + 0) * TSH;
        #pragma unroll
        for (int kb = 0; kb < 2; ++kb)
            #pragma unroll
            for (int m = 0; m < 2; ++m)
                areg[0][kb][m] = *reinterpret_cast<const f16x8*>(
                    &ap[((h128 * 4 + wrow * 2 + m) * 2 + kb) * 512 + lane8]);
        const short* bp = wfT + ((ks * 4 + 0) * 4 + 0) * TSH;
        #pragma unroll
        for (int kb = 0; kb < 2; ++kb)
            #pragma unroll
            for (int n = 0; n < 2; ++n)
                breg[0][kb][n] = *reinterpret_cast<const f16x8*>(
                    &bp[(kb * 8 + nt * 4 + wcol * 2 + n) * 512 + lane8]);
    }

    f32x4 acc[2][2];
    #pragma unroll
    for (int m = 0; m < 2; ++m)
        #pragma unroll
        for (int n = 0; n < 2; ++n)
            acc[m][n] = (f32x4){0.f, 0.f, 0.f, 0.f};

    #pragma unroll
    for (int c = 0; c < 4; ++c) {
        #pragma unroll
        for (int li = 0; li < 4; ++li) {
            const int s = c * 4 + li;

            if (s + 1 < NSTEP) {                       // prefetch B(s+1)
                const int sn = s + 1;
                const short* bp = wfT + ((ks * 4 + (sn & 3)) * 4 + (sn >> 2)) * TSH;
                #pragma unroll
                for (int kb = 0; kb < 2; ++kb)
                    #pragma unroll
                    for (int n = 0; n < 2; ++n)
                        breg[sn & 1][kb][n] = *reinterpret_cast<const f16x8*>(
                            &bp[(kb * 8 + nt * 4 + wcol * 2 + n) * 512 + lane8]);
            }
            if (li == 2 && c < 3) {                    // prefetch A(c+1)
                const short* ap = xh + (mt128 * 4 + c + 1) * TSH;
                #pragma unroll
                for (int kb = 0; kb < 2; ++kb)
                    #pragma unroll
                    for (int m = 0; m < 2; ++m)
                        areg[(c + 1) & 1][kb][m] = *reinterpret_cast<const f16x8*>(
                            &ap[((h128 * 4 + wrow * 2 + m) * 2 + kb) * 512 + lane8]);
            }

            #pragma unroll
            for (int kb = 0; kb < 2; ++kb) {
                f16x8 as_[2];
                #pragma unroll
                for (int m = 0; m < 2; ++m)
                    as_[m] = mulzw(areg[c & 1][kb][m], zwp[m][li]);
                #pragma unroll
                for (int m = 0; m < 2; ++m)
                    #pragma unroll
                    for (int n = 0; n < 2; ++n)
                        acc[m][n] = __builtin_amdgcn_mfma_f32_16x16x32_f16(
                            as_[m], breg[s & 1][kb][n], acc[m][n], 0, 0, 0);
            }
        }
    }

    // --- store f16 partial slice ---
    _Float16* dst = part + (size_t)ks * (B_SZ * U_SZ);
    #pragma unroll
    for (int m = 0; m < 2; ++m) {
        int row0 = R0 + wrow * 32 + m * 16 + ((lane >> 4) << 2);
        #pragma unroll
        for (int n = 0; n < 2; ++n) {
            int col = C0 + wcol * 32 + n * 16 + (lane & 15);
            #pragma unroll
            for (int j = 0; j < 4; ++j)
                dst[(row0 + j) * U_SZ + col] = (_Float16)acc[m][n][j];
        }
    }

    // --- split-K serialized epilogue ---
    __threadfence();                       // partials device-visible
    __syncthreads();
    if (tid == 0) oldc_s = atomicAdd(&cnt[q], 1);
    __syncthreads();
    if (oldc_s != KSPL - 1) return;        // uniform: only last block continues
    __threadfence();                       // acquire other blocks' partials

    // stage zb samples (64 rows x 32 l) and Bf slice (32 l x 64 u)
    #pragma unroll
    for (int it = 0; it < 8; ++it) {
        int e = it * 256 + tid;            // 2048 entries
        int r = e >> 5, l = e & 31;
        int b = R0 + r;
        int g = gid[b];
        zbs[r][l] = zb_mu[g * LB_SZ + l]
                  + softplus_f(zb_sigma[g * LB_SZ + l]) * eps_b[b * LB_SZ + l];
    }
    #pragma unroll
    for (int it = 0; it < 8; ++it) {
        int e = it * 256 + tid;            // 2048 entries
        int l = e >> 6, uu = e & 63;
        bfl[l][uu] = Bf[l * U_SZ + C0 + uu];
    }
    __syncthreads();

    const int r  = tid >> 2;               // 0..63
    const int u4 = (tid & 3) * 16;         // 0,16,32,48
    f32x4 a4[4];
    #pragma unroll
    for (int w = 0; w < 4; ++w) a4[w] = (f32x4){0.f, 0.f, 0.f, 0.f};

    #pragma unroll
    for (int l = 0; l < LB_SZ; ++l) {
        float z = zbs[r][l];
        #pragma unroll
        for (int w = 0; w < 4; ++w)
            a4[w] += z * *reinterpret_cast<const f32x4*>(&bfl[l][u4 + w * 4]);
    }
    #pragma unroll
    for (int kk = 0; kk < KSPL; ++kk) {
        const _Float16* pp = part + (size_t)kk * (B_SZ * U_SZ) + (R0 + r) * U_SZ + C0 + u4;
        f16x8 p0 = *reinterpret_cast<const f16x8*>(pp);
        f16x8 p1 = *reinterpret_cast<const f16x8*>(pp + 8);
        a4[0][0] += (float)p0[0]; a4[0][1] += (float)p0[1];
        a4[0][2] += (float)p0[2]; a4[0][3] += (float)p0[3];
        a4[1][0] += (float)p0[4]; a4[1][1] += (float)p0[5];
        a4[1][2] += (float)p0[6]; a4[1][3] += (float)p0[7];
        a4[2][0] += (float)p1[0]; a4[2][1] += (float)p1[1];
        a4[2][2] += (float)p1[2]; a4[2][3] += (float)p1[3];
        a4[3][0] += (float)p1[4]; a4[3][1] += (float)p1[5];
        a4[3][2] += (float)p1[6]; a4[3][3] += (float)p1[7];
    }
    float* op = &out[(R0 + r) * U_SZ + C0 + u4];
    #pragma unroll
    for (int w = 0; w < 4; ++w)
        *reinterpret_cast<f32x4*>(op + w * 4) = a4[w];
}

// ---------------------------------------------------------------------------
// Legacy fallback (no workspace): bias + atomic GEMM (bf16)
// ---------------------------------------------------------------------------
__global__ __launch_bounds__(256) void fmd_bias(
    const float* __restrict__ eps_b,
    const float* __restrict__ zb_mu,
    const float* __restrict__ zb_sigma,
    const float* __restrict__ Bf,
    const int*   __restrict__ gid,
    float*       __restrict__ out)
{
    const int half = threadIdx.x >> 7;
    const int u    = threadIdx.x & 127;
    const int b    = blockIdx.x * 2 + half;

    __shared__ float zb[2][LB_SZ];
    if (u < LB_SZ) {
        int g = gid[b];
        float sg = softplus_f(zb_sigma[g * LB_SZ + u]);
        zb[half][u] = zb_mu[g * LB_SZ + u] + sg * eps_b[b * LB_SZ + u];
    }
    __syncthreads();

    float acc = 0.0f;
    #pragma unroll
    for (int l = 0; l < LB_SZ; ++l)
        acc += zb[half][l] * Bf[l * U_SZ + u];
    out[b * U_SZ + u] = acc;
}

__global__ __launch_bounds__(256, 2) void fmd_gemm_legacy(
    const float* __restrict__ x,
    const float* __restrict__ eps_w,
    const float* __restrict__ zw_mu,
    const float* __restrict__ zw_sigma,
    const float* __restrict__ Wf,
    const int*   __restrict__ gid,
    float*       __restrict__ out)
{
    const int tid  = threadIdx.x;
    const int lane = tid & 63;
    const int wid  = tid >> 6;
    const int wr   = wid >> 1;
    const int wc   = wid & 1;
    const int bid  = blockIdx.x;
    const int ks   = bid & (KSPL - 1);
    const int mt   = bid >> 4;
    const int m0   = mt * 128;

    __shared__ short As[128 * 64];
    __shared__ short Bs[U_SZ * 64];
    __shared__ float zw_s[128][4];

    for (int it = tid; it < 128 * 4; it += 256) {
        int r = it >> 2, lloc = it & 3;
        int b = m0 + r;
        int g = gid[b];
        int l = ks * 4 + lloc;
        float sg = softplus_f(zw_sigma[g * LW_SZ + l]);
        zw_s[r][lloc] = zw_mu[g * LW_SZ + l] + sg * eps_w[b * LW_SZ + l];
    }

    f32x4 acc[4][4];
    #pragma unroll
    for (int m = 0; m < 4; ++m)
        #pragma unroll
        for (int n = 0; n < 4; ++n)
            acc[m][n] = (f32x4){0.f, 0.f, 0.f, 0.f};

    for (int s = 0; s < NSTEP; ++s) {
        __syncthreads();
        const int li = s >> 2;
        const int i0 = (s & 3) * 64;
        const int k0 = ks * (K_SZ / KSPL) + s * 64;

        #pragma unroll
        for (int it = 0; it < 8; ++it) {
            int idx = it * 256 + tid;
            int r = idx >> 4, c4 = idx & 15;
            float4 xv = *reinterpret_cast<const float4*>(&x[(m0 + r) * IN_SZ + i0 + c4 * 4]);
            float zw = zw_s[r][li];
            ushort h0 = f2bf(xv.x * zw), h1 = f2bf(xv.y * zw);
            ushort h2 = f2bf(xv.z * zw), h3 = f2bf(xv.w * zw);
            unsigned long long pw = (unsigned long long)h0
                                  | ((unsigned long long)h1 << 16)
                                  | ((unsigned long long)h2 << 32)
                                  | ((unsigned long long)h3 << 48);
            int si = (r * 64 + c4 * 4) ^ ((r & 7) << 3);
            *reinterpret_cast<unsigned long long*>(&As[si]) = pw;
        }
        #pragma unroll
        for (int it = 0; it < 4; ++it) {
            int idx = it * 256 + tid;
            int u = idx & 127, kg = idx >> 7;
            union { ushort h[8]; bf16x8 v; } pk;
            #pragma unroll
            for (int j = 0; j < 8; ++j)
                pk.h[j] = f2bf(Wf[(k0 + kg * 8 + j) * U_SZ + u]);
            int si = (u * 64 + kg * 8) ^ ((u & 7) << 3);
            *reinterpret_cast<bf16x8*>(&Bs[si]) = pk.v;
        }
        __syncthreads();

        #pragma unroll
        for (int kb = 0; kb < 2; ++kb) {
            bf16x8 af[4], bfr[4];
            #pragma unroll
            for (int m = 0; m < 4; ++m) {
                int row = wr * 64 + m * 16 + (lane & 15);
                int si = (row * 64 + kb * 32 + (lane >> 4) * 8) ^ ((row & 7) << 3);
                af[m] = *reinterpret_cast<const bf16x8*>(&As[si]);
            }
            #pragma unroll
            for (int n = 0; n < 4; ++n) {
                int rowu = wc * 64 + n * 16 + (lane & 15);
                int si = (rowu * 64 + kb * 32 + (lane >> 4) * 8) ^ ((rowu & 7) << 3);
                bfr[n] = *reinterpret_cast<const bf16x8*>(&Bs[si]);
            }
            #pragma unroll
            for (int m = 0; m < 4; ++m)
                #pragma unroll
                for (int n = 0; n < 4; ++n)
                    acc[m][n] = __builtin_amdgcn_mfma_f32_16x16x32_bf16(af[m], bfr[n], acc[m][n], 0, 0, 0);
        }
    }

    #pragma unroll
    for (int m = 0; m < 4; ++m) {
        int row0 = m0 + wr * 64 + m * 16 + ((lane >> 4) << 2);
        #pragma unroll
        for (int n = 0; n < 4; ++n) {
            int col = wc * 64 + n * 16 + (lane & 15);
            #pragma unroll
            for (int j = 0; j < 4; ++j)
                atomicAdd(&out[(row0 + j) * U_SZ + col], acc[m][n][j]);
        }
    }
}

extern "C" void kernel_launch(void* const* d_in, const int* in_sizes, int n_in,
                              void* d_out, int out_size, void* d_ws, size_t ws_size,
                              hipStream_t stream) {
    const float* x        = (const float*)d_in[0];
    const float* eps_w    = (const float*)d_in[1];
    const float* eps_b    = (const float*)d_in[2];
    const float* zw_mu    = (const float*)d_in[3];
    const float* zw_sigma = (const float*)d_in[4];
    const float* Wf       = (const float*)d_in[5];
    const float* zb_mu    = (const float*)d_in[6];
    const float* zb_sigma = (const float*)d_in[7];
    const float* Bf       = (const float*)d_in[8];
    const int*   gid      = (const int*)d_in[9];
    float* out = (float*)d_out;

    const size_t WFT_BYTES  = (size_t)K_SZ * U_SZ * 2;            // 4 MB
    const size_t XH_OFF     = WFT_BYTES;
    const size_t XH_BYTES   = (size_t)B_SZ * IN_SZ * 2;           // 2 MB
    const size_t PART_OFF   = XH_OFF + XH_BYTES;
    const size_t PART_BYTES = (size_t)KSPL * B_SZ * U_SZ * 2;     // 16 MB
    const size_t CNT_OFF    = PART_OFF + PART_BYTES;
    const size_t CNT_BYTES  = NQ * sizeof(int);

    if (ws_size >= CNT_OFF + CNT_BYTES) {
        short*     wfT  = (short*)d_ws;
        short*     xh   = (short*)((char*)d_ws + XH_OFF);
        _Float16*  part = (_Float16*)((char*)d_ws + PART_OFF);
        int*       cnt  = (int*)((char*)d_ws + CNT_OFF);
        fmd_prep7<<<769, 256, 0, stream>>>(Wf, x, wfT, xh, cnt);
        fmd_gemm7<<<NQ * KSPL, 256, 0, stream>>>(
            xh, wfT, zw_mu, zw_sigma, eps_w, gid,
            Bf, eps_b, zb_mu, zb_sigma, part, cnt, out);
    } else {
        fmd_bias<<<B_SZ / 2, 256, 0, stream>>>(eps_b, zb_mu, zb_sigma, Bf, gid, out);
        fmd_gemm_legacy<<<(B_SZ / 128) * KSPL, 256, 0, stream>>>(
            x, eps_w, zw_mu, zw_sigma, Wf, gid, out);
    }
}

// Round 9
// 43.203 us; speedup vs baseline: 9.9967x; 9.9967x over previous
//
#include <hip/hip_runtime.h>
#include <hip/hip_bf16.h>
#include <stdint.h>

// Problem constants
#define B_SZ   4096
#define IN_SZ  256
#define U_SZ   128
#define G_SZ   1000
#define LW_SZ  64
#define LB_SZ  32
#define K_SZ   (LW_SZ * IN_SZ)      // 16384

// out[B,U] = A[B,K] * Wf[K,U];  A[b, l*256+i] = zw[b,l] * x[b,i]
// LDS-free fragment-streaming GEMM (R6) + XCD producer/consumer alignment:
// gemm block bid = mt*16+ks lands on XCD ks%8 (round-robin dispatch); prep's
// wfT tile->block remap puts slab ks's 16 tiles on XCD ks%8 too, so the B
// operand is served from the SAME XCD's L2 instead of cross-XCD L3/HBM.
#define BM     128
#define KSPL   16                   // split over l: 4 l's per block
#define NSTEP  16                   // s = c*4 + li
#define NTILE  (K_SZ / 64)          // 256 wfT k-tiles
#define TSH    8192                 // shorts per tile (64k x 128u / 128r x 64k)

typedef __attribute__((ext_vector_type(8))) short  bf16x8;
typedef __attribute__((ext_vector_type(4))) float  f32x4;
typedef __attribute__((ext_vector_type(8))) _Float16 f16x8;
typedef __attribute__((ext_vector_type(4))) _Float16 f16x4;
typedef __attribute__((ext_vector_type(2))) _Float16 f16x2;

__device__ __forceinline__ ushort f2bf(float f) {
    unsigned u = __float_as_uint(f);
    u += 0x7fffu + ((u >> 16) & 1u);
    return (ushort)(u >> 16);
}

__device__ __forceinline__ float softplus_f(float v) {
    return fmaxf(v, 0.0f) + log1pf(__expf(-fabsf(v)));
}

__device__ __forceinline__ f16x8 mulzw(f16x8 a, f16x2 z) {
    union { f16x8 v8; f16x2 v2[4]; } in, out;
    in.v8 = a;
    #pragma unroll
    for (int w = 0; w < 4; ++w) out.v2[w] = in.v2[w] * z;   // v_pk_mul_f16
    return out.v8;
}

// ---------------------------------------------------------------------------
// Prep: fragment-order layouts (R6), with XCD-aligned wfT tile mapping.
//   wfT blocks bid in [0,256): t = ((bid&15)<<4) | (bid>>4)
//     -> slab s = t>>4 = bid&15, so bid%8 == s%8: all 16 tiles of slab s are
//        written from XCD s%8 == the consumer gemm blocks' XCD. [perf only]
//   xh blocks bid in [256,384): unchanged (xh is read by all XCDs -> L3).
// ---------------------------------------------------------------------------
__global__ __launch_bounds__(256) void fmd_prep(
    const float* __restrict__ Wf, const float* __restrict__ x,
    short* __restrict__ wfT, short* __restrict__ xh)
{
    const int tid = threadIdx.x;
    if (blockIdx.x < NTILE) {
        const int bid = blockIdx.x;
        const int t = ((bid & 15) << 4) | (bid >> 4);   // XCD-aligned remap
        __shared__ float lds[64 * 133];         // [kk][u], pad 133 (2-way max)
        #pragma unroll
        for (int it = 0; it < 8; ++it) {
            int idx = it * 256 + tid;           // 2048 float4 slots
            int kk = idx >> 5, u4 = idx & 31;
            float4 v = *reinterpret_cast<const float4*>(&Wf[(t * 64 + kk) * U_SZ + u4 * 4]);
            *reinterpret_cast<float4*>(&lds[kk * 133 + u4 * 4]) = v;
        }
        __syncthreads();
        short* tile = wfT + t * TSH;
        #pragma unroll
        for (int it = 0; it < 4; ++it) {
            int p = it * 256 + tid;             // 0..1023 f16x8 slots
            int kb  = p >> 9;
            int u16 = (p >> 6) & 7;
            int l   = p & 63;
            int u   = u16 * 16 + (l & 15);
            int kk0 = kb * 32 + (l >> 4) * 8;
            union { _Float16 h[8]; f16x8 v; } pk;
            #pragma unroll
            for (int j = 0; j < 8; ++j)
                pk.h[j] = (_Float16)lds[(kk0 + j) * 133 + u];
            *reinterpret_cast<f16x8*>(&tile[p * 8]) = pk.v;
        }
    } else {
        const int bb = blockIdx.x - NTILE;      // 0..127 : (mtile, chunk)
        const int mt = bb >> 2, c = bb & 3;
        short* tile = xh + bb * TSH;
        #pragma unroll
        for (int it = 0; it < 4; ++it) {
            int p = it * 256 + tid;             // 0..1023 f16x8 slots
            int frag = p >> 6;                  // (wr*4+m)*2+kb
            int l    = p & 63;
            int wr2  = frag >> 3;
            int m2   = (frag >> 1) & 3;
            int kb   = frag & 1;
            int row  = mt * 128 + wr2 * 64 + m2 * 16 + (l & 15);
            int col  = c * 64 + kb * 32 + (l >> 4) * 8;
            const float* src = &x[row * IN_SZ + col];
            float4 a = *reinterpret_cast<const float4*>(src);
            float4 b = *reinterpret_cast<const float4*>(src + 4);
            union { _Float16 h[8]; f16x8 v; } pk;
            pk.h[0] = (_Float16)a.x; pk.h[1] = (_Float16)a.y;
            pk.h[2] = (_Float16)a.z; pk.h[3] = (_Float16)a.w;
            pk.h[4] = (_Float16)b.x; pk.h[5] = (_Float16)b.y;
            pk.h[6] = (_Float16)b.z; pk.h[7] = (_Float16)b.w;
            *reinterpret_cast<f16x8*>(&tile[p * 8]) = pk.v;
        }
    }
}

// ---------------------------------------------------------------------------
// GEMM v6 (LDS-free, verbatim R6): 512 blocks (32 mt x 16 ks), 4 waves,
// 64x64 wave tile. Fragments loaded global->register, coalesced dwordx4;
// double-buffered; prefetch next step during MFMA. bid%8 == ks%8 -> B slab
// L2-local after the prep remap.
// ---------------------------------------------------------------------------
__global__ __launch_bounds__(256, 2) void fmd_gemm6(
    const short* __restrict__ xh,
    const short* __restrict__ wfT,
    const float* __restrict__ zw_mu,
    const float* __restrict__ zw_sigma,
    const float* __restrict__ eps_w,
    const int*   __restrict__ gid,
    _Float16*    __restrict__ part)
{
    const int tid  = threadIdx.x;
    const int lane = tid & 63;
    const int wid  = tid >> 6;
    const int wr   = wid >> 1;
    const int wc   = wid & 1;
    const int bid  = blockIdx.x;
    const int ks   = bid & (KSPL - 1);
    const int mt   = bid >> 4;
    const int m0   = mt * BM;
    const int lane8 = lane * 8;

    // --- per-lane packed zw for its 4 rows x 4 li ---
    f16x2 zwp[4][4];
    #pragma unroll
    for (int m = 0; m < 4; ++m) {
        int row = wr * 64 + m * 16 + (lane & 15);
        int b   = m0 + row;
        int g   = gid[b];
        float4 mu = *reinterpret_cast<const float4*>(&zw_mu[g * LW_SZ + ks * 4]);
        float4 sg = *reinterpret_cast<const float4*>(&zw_sigma[g * LW_SZ + ks * 4]);
        float4 ep = *reinterpret_cast<const float4*>(&eps_w[b * LW_SZ + ks * 4]);
        float v0 = mu.x + softplus_f(sg.x) * ep.x;
        float v1 = mu.y + softplus_f(sg.y) * ep.y;
        float v2 = mu.z + softplus_f(sg.z) * ep.z;
        float v3 = mu.w + softplus_f(sg.w) * ep.w;
        _Float16 h0 = (_Float16)v0, h1 = (_Float16)v1, h2 = (_Float16)v2, h3 = (_Float16)v3;
        zwp[m][0] = (f16x2){h0, h0};
        zwp[m][1] = (f16x2){h1, h1};
        zwp[m][2] = (f16x2){h2, h2};
        zwp[m][3] = (f16x2){h3, h3};
    }

    f16x8 areg[2][2][4];   // [c&1][kb][m]
    f16x8 breg[2][2][4];   // [s&1][kb][n]

    // prologue: A(c=0), B(s=0)
    {
        const short* ap = xh + (mt * 4 + 0) * TSH;
        #pragma unroll
        for (int kb = 0; kb < 2; ++kb)
            #pragma unroll
            for (int m = 0; m < 4; ++m)
                areg[0][kb][m] = *reinterpret_cast<const f16x8*>(
                    &ap[((wr * 4 + m) * 2 + kb) * 512 + lane8]);
        const short* bp = wfT + ((ks * 4 + 0) * 4 + 0) * TSH;
        #pragma unroll
        for (int kb = 0; kb < 2; ++kb)
            #pragma unroll
            for (int n = 0; n < 4; ++n)
                breg[0][kb][n] = *reinterpret_cast<const f16x8*>(
                    &bp[(kb * 8 + wc * 4 + n) * 512 + lane8]);
    }

    f32x4 acc[4][4];
    #pragma unroll
    for (int m = 0; m < 4; ++m)
        #pragma unroll
        for (int n = 0; n < 4; ++n)
            acc[m][n] = (f32x4){0.f, 0.f, 0.f, 0.f};

    #pragma unroll
    for (int c = 0; c < 4; ++c) {
        #pragma unroll
        for (int li = 0; li < 4; ++li) {
            const int s = c * 4 + li;

            if (s + 1 < NSTEP) {                       // prefetch B(s+1)
                const int sn = s + 1;
                const short* bp = wfT + ((ks * 4 + (sn & 3)) * 4 + (sn >> 2)) * TSH;
                #pragma unroll
                for (int kb = 0; kb < 2; ++kb)
                    #pragma unroll
                    for (int n = 0; n < 4; ++n)
                        breg[sn & 1][kb][n] = *reinterpret_cast<const f16x8*>(
                            &bp[(kb * 8 + wc * 4 + n) * 512 + lane8]);
            }
            if (li == 2 && c < 3) {                    // prefetch A(c+1)
                const short* ap = xh + (mt * 4 + c + 1) * TSH;
                #pragma unroll
                for (int kb = 0; kb < 2; ++kb)
                    #pragma unroll
                    for (int m = 0; m < 4; ++m)
                        areg[(c + 1) & 1][kb][m] = *reinterpret_cast<const f16x8*>(
                            &ap[((wr * 4 + m) * 2 + kb) * 512 + lane8]);
            }

            #pragma unroll
            for (int kb = 0; kb < 2; ++kb) {
                f16x8 as_[4];
                #pragma unroll
                for (int m = 0; m < 4; ++m)
                    as_[m] = mulzw(areg[c & 1][kb][m], zwp[m][li]);
                #pragma unroll
                for (int m = 0; m < 4; ++m)
                    #pragma unroll
                    for (int n = 0; n < 4; ++n)
                        acc[m][n] = __builtin_amdgcn_mfma_f32_16x16x32_f16(
                            as_[m], breg[s & 1][kb][n], acc[m][n], 0, 0, 0);
            }
        }
    }

    // --- epilogue: f16 partials, slice ks ---
    _Float16* dst = part + (size_t)ks * (B_SZ * U_SZ);
    #pragma unroll
    for (int m = 0; m < 4; ++m) {
        int row0 = m0 + wr * 64 + m * 16 + ((lane >> 4) << 2);
        #pragma unroll
        for (int n = 0; n < 4; ++n) {
            int col = wc * 64 + n * 16 + (lane & 15);
            #pragma unroll
            for (int j = 0; j < 4; ++j)
                dst[(row0 + j) * U_SZ + col] = (_Float16)acc[m][n][j];
        }
    }
}

// ---------------------------------------------------------------------------
// Reduce + bias: out[b,u] = sum_ks part[ks][b][u] + bias[b,u].
// 8 outputs/thread. Overwrites d_out fully (poison reset).
// ---------------------------------------------------------------------------
__global__ __launch_bounds__(256) void fmd_reduce4(
    const _Float16* __restrict__ part,
    const float* __restrict__ eps_b,
    const float* __restrict__ zb_mu,
    const float* __restrict__ zb_sigma,
    const float* __restrict__ Bf,
    const int*   __restrict__ gid,
    float*       __restrict__ out)
{
    const int tid = threadIdx.x;
    const int bid = blockIdx.x;               // 256 blocks
    const int i8  = bid * 256 + tid;          // 8-elem unit index (65536 total)
    const int r   = tid >> 4;                 // local b row 0..15
    const int u0  = (tid & 15) * 8;           // u start

    __shared__ float zb[16][33];
    {
        int e = tid;                          // 2 entries per thread (512 total)
        int rr = e >> 5, cc = e & 31;
        int b2 = bid * 16 + rr;
        int g  = gid[b2];
        zb[rr][cc] = zb_mu[g * LB_SZ + cc]
                   + softplus_f(zb_sigma[g * LB_SZ + cc]) * eps_b[b2 * LB_SZ + cc];
        e += 256; rr = e >> 5; cc = e & 31;
        b2 = bid * 16 + rr;
        g  = gid[b2];
        zb[rr][cc] = zb_mu[g * LB_SZ + cc]
                   + softplus_f(zb_sigma[g * LB_SZ + cc]) * eps_b[b2 * LB_SZ + cc];
    }
    __syncthreads();

    f32x4 a0 = (f32x4){0.f, 0.f, 0.f, 0.f};
    f32x4 a1 = (f32x4){0.f, 0.f, 0.f, 0.f};
    #pragma unroll
    for (int l = 0; l < LB_SZ; ++l) {
        float z = zb[r][l];
        f32x4 b0 = *reinterpret_cast<const f32x4*>(&Bf[l * U_SZ + u0]);
        f32x4 b1 = *reinterpret_cast<const f32x4*>(&Bf[l * U_SZ + u0 + 4]);
        a0 += z * b0;
        a1 += z * b1;
    }

    #pragma unroll
    for (int ks = 0; ks < KSPL; ++ks) {
        f16x8 p = *reinterpret_cast<const f16x8*>(
            &part[(size_t)ks * (B_SZ * U_SZ) + (size_t)i8 * 8]);
        a0[0] += (float)p[0]; a0[1] += (float)p[1];
        a0[2] += (float)p[2]; a0[3] += (float)p[3];
        a1[0] += (float)p[4]; a1[1] += (float)p[5];
        a1[2] += (float)p[6]; a1[3] += (float)p[7];
    }
    *reinterpret_cast<f32x4*>(&out[(size_t)i8 * 8])     = a0;
    *reinterpret_cast<f32x4*>(&out[(size_t)i8 * 8 + 4]) = a1;
}

// ---------------------------------------------------------------------------
// Legacy fallback (no workspace): bias + atomic GEMM (bf16)
// ---------------------------------------------------------------------------
__global__ __launch_bounds__(256) void fmd_bias(
    const float* __restrict__ eps_b,
    const float* __restrict__ zb_mu,
    const float* __restrict__ zb_sigma,
    const float* __restrict__ Bf,
    const int*   __restrict__ gid,
    float*       __restrict__ out)
{
    const int half = threadIdx.x >> 7;
    const int u    = threadIdx.x & 127;
    const int b    = blockIdx.x * 2 + half;

    __shared__ float zb[2][LB_SZ];
    if (u < LB_SZ) {
        int g = gid[b];
        float sg = softplus_f(zb_sigma[g * LB_SZ + u]);
        zb[half][u] = zb_mu[g * LB_SZ + u] + sg * eps_b[b * LB_SZ + u];
    }
    __syncthreads();

    float acc = 0.0f;
    #pragma unroll
    for (int l = 0; l < LB_SZ; ++l)
        acc += zb[half][l] * Bf[l * U_SZ + u];
    out[b * U_SZ + u] = acc;
}

__global__ __launch_bounds__(256, 2) void fmd_gemm_legacy(
    const float* __restrict__ x,
    const float* __restrict__ eps_w,
    const float* __restrict__ zw_mu,
    const float* __restrict__ zw_sigma,
    const float* __restrict__ Wf,
    const int*   __restrict__ gid,
    float*       __restrict__ out)
{
    const int tid  = threadIdx.x;
    const int lane = tid & 63;
    const int wid  = tid >> 6;
    const int wr   = wid >> 1;
    const int wc   = wid & 1;
    const int bid  = blockIdx.x;
    const int ks   = bid & (KSPL - 1);
    const int mt   = bid >> 4;
    const int m0   = mt * 128;

    __shared__ short As[128 * 64];
    __shared__ short Bs[U_SZ * 64];
    __shared__ float zw_s[128][4];

    for (int it = tid; it < 128 * 4; it += 256) {
        int r = it >> 2, lloc = it & 3;
        int b = m0 + r;
        int g = gid[b];
        int l = ks * 4 + lloc;
        float sg = softplus_f(zw_sigma[g * LW_SZ + l]);
        zw_s[r][lloc] = zw_mu[g * LW_SZ + l] + sg * eps_w[b * LW_SZ + l];
    }

    f32x4 acc[4][4];
    #pragma unroll
    for (int m = 0; m < 4; ++m)
        #pragma unroll
        for (int n = 0; n < 4; ++n)
            acc[m][n] = (f32x4){0.f, 0.f, 0.f, 0.f};

    for (int s = 0; s < NSTEP; ++s) {
        __syncthreads();
        const int li = s >> 2;
        const int i0 = (s & 3) * 64;
        const int k0 = ks * (K_SZ / KSPL) + s * 64;

        #pragma unroll
        for (int it = 0; it < 8; ++it) {
            int idx = it * 256 + tid;
            int r = idx >> 4, c4 = idx & 15;
            float4 xv = *reinterpret_cast<const float4*>(&x[(m0 + r) * IN_SZ + i0 + c4 * 4]);
            float zw = zw_s[r][li];
            ushort h0 = f2bf(xv.x * zw), h1 = f2bf(xv.y * zw);
            ushort h2 = f2bf(xv.z * zw), h3 = f2bf(xv.w * zw);
            unsigned long long pw = (unsigned long long)h0
                                  | ((unsigned long long)h1 << 16)
                                  | ((unsigned long long)h2 << 32)
                                  | ((unsigned long long)h3 << 48);
            int si = (r * 64 + c4 * 4) ^ ((r & 7) << 3);
            *reinterpret_cast<unsigned long long*>(&As[si]) = pw;
        }
        #pragma unroll
        for (int it = 0; it < 4; ++it) {
            int idx = it * 256 + tid;
            int u = idx & 127, kg = idx >> 7;
            union { ushort h[8]; bf16x8 v; } pk;
            #pragma unroll
            for (int j = 0; j < 8; ++j)
                pk.h[j] = f2bf(Wf[(k0 + kg * 8 + j) * U_SZ + u]);
            int si = (u * 64 + kg * 8) ^ ((u & 7) << 3);
            *reinterpret_cast<bf16x8*>(&Bs[si]) = pk.v;
        }
        __syncthreads();

        #pragma unroll
        for (int kb = 0; kb < 2; ++kb) {
            bf16x8 af[4], bfr[4];
            #pragma unroll
            for (int m = 0; m < 4; ++m) {
                int row = wr * 64 + m * 16 + (lane & 15);
                int si = (row * 64 + kb * 32 + (lane >> 4) * 8) ^ ((row & 7) << 3);
                af[m] = *reinterpret_cast<const bf16x8*>(&As[si]);
            }
            #pragma unroll
            for (int n = 0; n < 4; ++n) {
                int rowu = wc * 64 + n * 16 + (lane & 15);
                int si = (rowu * 64 + kb * 32 + (lane >> 4) * 8) ^ ((rowu & 7) << 3);
                bfr[n] = *reinterpret_cast<const bf16x8*>(&Bs[si]);
            }
            #pragma unroll
            for (int m = 0; m < 4; ++m)
                #pragma unroll
                for (int n = 0; n < 4; ++n)
                    acc[m][n] = __builtin_amdgcn_mfma_f32_16x16x32_bf16(af[m], bfr[n], acc[m][n], 0, 0, 0);
        }
    }

    #pragma unroll
    for (int m = 0; m < 4; ++m) {
        int row0 = m0 + wr * 64 + m * 16 + ((lane >> 4) << 2);
        #pragma unroll
        for (int n = 0; n < 4; ++n) {
            int col = wc * 64 + n * 16 + (lane & 15);
            #pragma unroll
            for (int j = 0; j < 4; ++j)
                atomicAdd(&out[(row0 + j) * U_SZ + col], acc[m][n][j]);
        }
    }
}

extern "C" void kernel_launch(void* const* d_in, const int* in_sizes, int n_in,
                              void* d_out, int out_size, void* d_ws, size_t ws_size,
                              hipStream_t stream) {
    const float* x        = (const float*)d_in[0];
    const float* eps_w    = (const float*)d_in[1];
    const float* eps_b    = (const float*)d_in[2];
    const float* zw_mu    = (const float*)d_in[3];
    const float* zw_sigma = (const float*)d_in[4];
    const float* Wf       = (const float*)d_in[5];
    const float* zb_mu    = (const float*)d_in[6];
    const float* zb_sigma = (const float*)d_in[7];
    const float* Bf       = (const float*)d_in[8];
    const int*   gid      = (const int*)d_in[9];
    float* out = (float*)d_out;

    const size_t WFT_BYTES  = (size_t)K_SZ * U_SZ * 2;            // 4 MB
    const size_t XH_OFF     = WFT_BYTES;
    const size_t XH_BYTES   = (size_t)B_SZ * IN_SZ * 2;           // 2 MB
    const size_t PART_OFF   = XH_OFF + XH_BYTES;
    const size_t PART_BYTES = (size_t)KSPL * B_SZ * U_SZ * 2;     // 16 MB

    if (ws_size >= PART_OFF + PART_BYTES) {
        short*     wfT  = (short*)d_ws;
        short*     xh   = (short*)((char*)d_ws + XH_OFF);
        _Float16*  part = (_Float16*)((char*)d_ws + PART_OFF);
        fmd_prep<<<NTILE + (B_SZ / BM) * 4, 256, 0, stream>>>(Wf, x, wfT, xh);
        fmd_gemm6<<<(B_SZ / BM) * KSPL, 256, 0, stream>>>(
            xh, wfT, zw_mu, zw_sigma, eps_w, gid, part);
        fmd_reduce4<<<(B_SZ * U_SZ) / 2048, 256, 0, stream>>>(
            part, eps_b, zb_mu, zb_sigma, Bf, gid, out);
    } else {
        fmd_bias<<<B_SZ / 2, 256, 0, stream>>>(eps_b, zb_mu, zb_sigma, Bf, gid, out);
        fmd_gemm_legacy<<<(B_SZ / 128) * KSPL, 256, 0, stream>>>(
            x, eps_w, zw_mu, zw_sigma, Wf, gid, out);
    }
}